// Round 3
// baseline (160.152 us; speedup 1.0000x reference)
//
#include <hip/hip_runtime.h>
#include <hip/hip_cooperative_groups.h>

namespace cg = cooperative_groups;

#define N_NODES 8192
#define NODE_DIM 128
#define HIDDEN_DIM 256
#define CAP 96              // rowlist stride; raw count/row ~Poisson(16), P(>=96) ~ 1e-40
#define RPB 16              // rows per block in fused kernel
#define YLD 136             // LDS row stride in shorts (272 B: 16B-aligned, 2-way-conflict free)

typedef __attribute__((ext_vector_type(8))) short bf16x8;
typedef __attribute__((ext_vector_type(4))) float f32x4;

static __device__ __forceinline__ unsigned short f2bf(float f) {
    unsigned u = __builtin_bit_cast(unsigned, f);
    unsigned r = u + 0x7fffu + ((u >> 16) & 1u);   // RNE
    return (unsigned short)(r >> 16);
}
static __device__ __forceinline__ float bf2f(unsigned short h) {
    unsigned u = ((unsigned)h) << 16;
    return __builtin_bit_cast(float, u);
}

// ---------------------------------------------------------------------------
// Kernel 1 (COOPERATIVE, 256 blocks x 512 = 131072 threads, 1 block/CU so
// co-residency is guaranteed):
//  Phase 0: zero deg (32 KB -> kills the hipMemsetAsync dispatch) and convert
//           W -> split bf16 (Wh + Wl) on disjoint thread ranges.
//  Phase 1: optimistic append — p = atomicAdd(&deg[s]); rowlist[s*CAP+p] = t.
//           Duplicates (~128 expected of 131072) tolerated here.
//  Phase 2: per-wave dedupe+compact via __shfl (no LDS): 4 rows/wave, O(n^2)
//           register compares, ballot-compact rowlist in place, overwrite
//           deg[i] with the DISTINCT count (the semantic the fused kernel
//           needs). Raw clamp 64: P(Poisson(16) >= 64) ~ 1e-18.
// Replaces 3 dispatches (memset + append + compact) with 1 + 2 grid syncs.
// ---------------------------------------------------------------------------
__global__ __launch_bounds__(512)
void build_kernel(const int* __restrict__ e,
                  unsigned int* __restrict__ deg,
                  int* __restrict__ rowlist,
                  const float* __restrict__ W,
                  unsigned short* __restrict__ wh,
                  unsigned short* __restrict__ wl,
                  int E) {
    cg::grid_group grid = cg::this_grid();
    int gtid = (int)(blockIdx.x * 512 + threadIdx.x);   // 0..131071

    // ---- Phase 0: zero deg + split-bf16 W (disjoint ranges) ----
    if (gtid < N_NODES) deg[gtid] = 0u;
    int wi = gtid - N_NODES;
    if (wi >= 0 && wi < HIDDEN_DIM * NODE_DIM / 4) {
        float4 v = ((const float4*)W)[wi];
        ushort4 h, l;
        h.x = f2bf(v.x); l.x = f2bf(v.x - bf2f(h.x));
        h.y = f2bf(v.y); l.y = f2bf(v.y - bf2f(h.y));
        h.z = f2bf(v.z); l.z = f2bf(v.z - bf2f(h.z));
        h.w = f2bf(v.w); l.w = f2bf(v.w - bf2f(h.w));
        ((ushort4*)wh)[wi] = h;
        ((ushort4*)wl)[wi] = l;
    }
    grid.sync();

    // ---- Phase 1: append all edges ----
    for (int idx = gtid; idx < E; idx += 256 * 512) {
        int s = e[idx];        // row (src)
        int t = e[E + idx];    // col (tgt)
        unsigned int p = atomicAdd(&deg[s], 1u);
        if (p < CAP) rowlist[(size_t)s * CAP + p] = t;
    }
    grid.sync();

    // ---- Phase 2: per-wave dedupe + compact, 4 rows per wave ----
    {
        int lane = (int)(threadIdx.x & 63);
        int wgl  = gtid >> 6;            // global wave 0..2047
#pragma unroll
        for (int rr = 0; rr < 4; ++rr) {
            int i = wgl * 4 + rr;        // row 0..8191
            int n = (int)deg[i];
            if (n > 64) n = 64;
            int t = (lane < n) ? rowlist[(size_t)i * CAP + lane] : -1;
            bool keep = (lane < n);
            for (int j = 0; j + 1 < n; ++j) {      // n is wave-uniform
                int tj = __shfl(t, j);
                if (j < lane && tj == t) keep = false;
            }
            unsigned long long m = __ballot(keep);
            int pos = __popcll(m & ((1ull << lane) - 1ull));
            if (keep && pos != lane) rowlist[(size_t)i * CAP + pos] = t;  // src vals in regs
            if (lane == 0) deg[i] = (unsigned int)__popcll(m);
        }
    }
}

// ---------------------------------------------------------------------------
// Kernel 2 (FUSED aggregate + GEMM): each block owns 16 output rows.
// Phase A: stage neighbor lists + dj = rsqrt(deg+1) in LDS; one 32-lane team
//   per row gathers x via float4, computes y[i] = di*(di*x[i] + sum_j dj*x[j])
//   and stores split-bf16 Y tile in LDS.
//   Self-edge j==i appears in list with dj==di plus identity term -> A~[i][i]=2. OK.
// Phase B: 8 waves; wave w computes out[16 x 32] cols w*32.. via split-bf16
//   MFMA (Yh*Wh + Yh*Wl + Yl*Wh; Yl*Wl ~1e-5 rel, dropped).
// ---------------------------------------------------------------------------
__global__ __launch_bounds__(512)
void fused_agg_gemm(const int* __restrict__ rowlist,
                    const unsigned int* __restrict__ deg,
                    const float* __restrict__ x,
                    const unsigned short* __restrict__ Wh,
                    const unsigned short* __restrict__ Wl,
                    float* __restrict__ out) {
    __shared__ int            nrow[RPB];
    __shared__ float          sdi[RPB];
    __shared__ int            cols[RPB][CAP];
    __shared__ float          djs[RPB][CAP];
    __shared__ unsigned short Yh[RPB][YLD];
    __shared__ unsigned short Yl[RPB][YLD];

    int tid = threadIdx.x;
    int m0  = blockIdx.x * RPB;

    if (tid < RPB) {
        unsigned int dg = deg[m0 + tid];   // distinct count (post-compact)
        int n = (int)dg; if (n > CAP) n = CAP;
        nrow[tid] = n;
        sdi[tid]  = rsqrtf((float)dg + 1.0f);
    }
    __syncthreads();

    // stage neighbor ids + dj factors (scattered deg loads, ~272 per block)
    for (int e = tid; e < RPB * CAP; e += 512) {
        int r = e / CAP, k = e - r * CAP;
        if (k < nrow[r]) {
            int c = rowlist[(size_t)(m0 + r) * CAP + k];
            cols[r][k] = c;
            djs[r][k]  = rsqrtf((float)deg[c] + 1.0f);
        }
    }
    __syncthreads();

    // ---- Phase A: gather + normalize, one 32-lane team per row ----
    {
        int team = tid >> 5;       // row within tile (0..15)
        int l4   = tid & 31;       // float4 slot (32*4 = 128 dims)
        const float4* x4 = (const float4*)x;
        int   n    = nrow[team];
        float di   = sdi[team];
        float4 self = x4[(size_t)(m0 + team) * 32 + l4];
        float ax = 0.f, ay = 0.f, az = 0.f, aw = 0.f;
        int k = 0;
        for (; k + 2 <= n; k += 2) {           // unroll-by-2 for memory ILP
            float  d0 = djs[team][k];
            float  d1 = djs[team][k + 1];
            float4 v0 = x4[(size_t)cols[team][k]     * 32 + l4];
            float4 v1 = x4[(size_t)cols[team][k + 1] * 32 + l4];
            ax += d0 * v0.x + d1 * v1.x;
            ay += d0 * v0.y + d1 * v1.y;
            az += d0 * v0.z + d1 * v1.z;
            aw += d0 * v0.w + d1 * v1.w;
        }
        if (k < n) {
            float  d0 = djs[team][k];
            float4 v0 = x4[(size_t)cols[team][k] * 32 + l4];
            ax += d0 * v0.x; ay += d0 * v0.y; az += d0 * v0.z; aw += d0 * v0.w;
        }
        float vx = di * (di * self.x + ax);
        float vy = di * (di * self.y + ay);
        float vz = di * (di * self.z + az);
        float vw = di * (di * self.w + aw);
        ushort4 h, l;
        h.x = f2bf(vx); l.x = f2bf(vx - bf2f(h.x));
        h.y = f2bf(vy); l.y = f2bf(vy - bf2f(h.y));
        h.z = f2bf(vz); l.z = f2bf(vz - bf2f(h.z));
        h.w = f2bf(vw); l.w = f2bf(vw - bf2f(h.w));
        *(ushort4*)&Yh[team][l4 * 4] = h;
        *(ushort4*)&Yl[team][l4 * 4] = l;
    }
    __syncthreads();

    // ---- Phase B: 16x256 = Y[16][128] @ W[256][128]^T, split-bf16 MFMA ----
    // Frag layout (16x16x32_bf16): A[m=lane&15][k=quad*8+j]; C/D col=lane&15,
    // row=quad*4+reg (same conventions as the previously-verified gemm_kernel).
    {
        int wave = tid >> 6;      // 0..7, owns cols wave*32 .. wave*32+31
        int lane = tid & 63;
        int quad = lane >> 4;
        int l16  = lane & 15;

        f32x4 acc[2] = {{0,0,0,0},{0,0,0,0}};
#pragma unroll
        for (int ks = 0; ks < 4; ++ks) {
            bf16x8 ah = *(const bf16x8*)&Yh[l16][ks * 32 + quad * 8];
            bf16x8 al = *(const bf16x8*)&Yl[l16][ks * 32 + quad * 8];
#pragma unroll
            for (int ct = 0; ct < 2; ++ct) {
                int hcol = wave * 32 + ct * 16 + l16;
                bf16x8 bh = *(const bf16x8*)(Wh + (size_t)hcol * NODE_DIM + ks * 32 + quad * 8);
                bf16x8 bl = *(const bf16x8*)(Wl + (size_t)hcol * NODE_DIM + ks * 32 + quad * 8);
                acc[ct] = __builtin_amdgcn_mfma_f32_16x16x32_bf16(ah, bh, acc[ct], 0, 0, 0);
                acc[ct] = __builtin_amdgcn_mfma_f32_16x16x32_bf16(ah, bl, acc[ct], 0, 0, 0);
                acc[ct] = __builtin_amdgcn_mfma_f32_16x16x32_bf16(al, bh, acc[ct], 0, 0, 0);
            }
        }
#pragma unroll
        for (int ct = 0; ct < 2; ++ct) {
#pragma unroll
            for (int r = 0; r < 4; ++r) {
                out[(size_t)(m0 + quad * 4 + r) * HIDDEN_DIM + wave * 32 + ct * 16 + l16] = acc[ct][r];
            }
        }
    }
}

extern "C" void kernel_launch(void* const* d_in, const int* in_sizes, int n_in,
                              void* d_out, int out_size, void* d_ws, size_t ws_size,
                              hipStream_t stream) {
    const float* x = (const float*)d_in[0];
    const int*   e = (const int*)d_in[1];   // edge_index delivered as int32 [2, E]
    const float* W = (const float*)d_in[2];
    float*       out = (float*)d_out;
    int E = in_sizes[1] / 2;

    // ws layout: deg 32KB | rowlist 3MB | wh 64KB | wl 64KB
    unsigned int*   deg     = (unsigned int*)d_ws;
    int*            rowlist = (int*)(deg + N_NODES);
    unsigned short* wh      = (unsigned short*)(rowlist + (size_t)N_NODES * CAP);
    unsigned short* wl      = wh + (size_t)HIDDEN_DIM * NODE_DIM;

    // Cooperative build: zero+Wconv / append / compact with 2 grid syncs.
    // 256 blocks x 512 threads = 1 block/CU -> co-residency guaranteed.
    {
        const int*      e_arg  = e;
        unsigned int*   d_arg  = deg;
        int*            r_arg  = rowlist;
        const float*    W_arg  = W;
        unsigned short* wh_arg = wh;
        unsigned short* wl_arg = wl;
        int             E_arg  = E;
        void* args[] = {(void*)&e_arg, (void*)&d_arg, (void*)&r_arg,
                        (void*)&W_arg, (void*)&wh_arg, (void*)&wl_arg, (void*)&E_arg};
        hipLaunchCooperativeKernel((const void*)build_kernel, dim3(256), dim3(512),
                                   args, 0, stream);
    }
    fused_agg_gemm<<<N_NODES / RPB, 512, 0, stream>>>(rowlist, deg, x, wh, wl, out);
}

// Round 4
// 89.964 us; speedup vs baseline: 1.7802x; 1.7802x over previous
//
#include <hip/hip_runtime.h>

#define N_NODES 8192
#define NODE_DIM 128
#define HIDDEN_DIM 256
#define CAP 96              // rowlist stride; raw count/row ~Poisson(16), P(>=96) ~ 1e-40
#define RPB 16              // rows per block in fused kernel
#define YLD 136             // LDS row stride in shorts (272 B: 16B-aligned, 2-way-conflict free)

typedef __attribute__((ext_vector_type(8))) short bf16x8;
typedef __attribute__((ext_vector_type(4))) float f32x4;

static __device__ __forceinline__ unsigned short f2bf(float f) {
    unsigned u = __builtin_bit_cast(unsigned, f);
    unsigned r = u + 0x7fffu + ((u >> 16) & 1u);   // RNE
    return (unsigned short)(r >> 16);
}
static __device__ __forceinline__ float bf2f(unsigned short h) {
    unsigned u = ((unsigned)h) << 16;
    return __builtin_bit_cast(float, u);
}

// ---------------------------------------------------------------------------
// Kernel 1 (blocks < nEdgeBlocks): OPTIMISTIC append — no bitmask, no 8MB
// memset, no scattered atomicOr RMW chain. Every edge appended:
//   p = atomicAdd(&deg[s]) (32KB hot array); rowlist[s*CAP+p] = t.
// Duplicates (~128 expected of 131072) are removed row-locally by Kernel 2.
// Kernel 1 (trailing 32 blocks): W -> split bf16 (Wh + Wl), fused here.
// NOTE (R3 post-mortem): do NOT replace these kernel boundaries with
// cooperative grid.sync() — measured ~30 us per sync on MI355X (global
// spin barrier across 8 non-coherent XCD L2s) vs ~1 us per boundary.
// ---------------------------------------------------------------------------
__global__ void append_kernel(const int* __restrict__ e,
                              unsigned int* __restrict__ deg,
                              int* __restrict__ rowlist,
                              const float* __restrict__ W,
                              unsigned short* __restrict__ wh,
                              unsigned short* __restrict__ wl,
                              int E, int nEdgeBlocks) {
    if ((int)blockIdx.x < nEdgeBlocks) {
        int idx = blockIdx.x * 256 + threadIdx.x;
        if (idx >= E) return;
        int s = e[idx];        // row (src)
        int t = e[E + idx];    // col (tgt)
        unsigned int p = atomicAdd(&deg[s], 1u);
        if (p < CAP) rowlist[(size_t)s * CAP + p] = t;
    } else {
        int t = (blockIdx.x - nEdgeBlocks) * 256 + threadIdx.x;  // float4 idx, 8192 total
        if (t >= HIDDEN_DIM * NODE_DIM / 4) return;
        float4 v = ((const float4*)W)[t];
        ushort4 h, l;
        h.x = f2bf(v.x); l.x = f2bf(v.x - bf2f(h.x));
        h.y = f2bf(v.y); l.y = f2bf(v.y - bf2f(h.y));
        h.z = f2bf(v.z); l.z = f2bf(v.z - bf2f(h.z));
        h.w = f2bf(v.w); l.w = f2bf(v.w - bf2f(h.w));
        ((ushort4*)wh)[t] = h;
        ((ushort4*)wl)[t] = l;
    }
}

// ---------------------------------------------------------------------------
// Kernel 2 (compact): one wave per row. Dedupe the ~16-entry list in LDS
// (O(n^2) ~ 128 LDS compares), ballot-compact rowlist in place, overwrite
// deg[i] with the DISTINCT count (the semantic the fused kernel needs).
// Raw-count clamp 64: P(Poisson(16) >= 64) ~ 1e-18 -> never in practice.
// This boundary is REQUIRED: fused blocks read rsqrt(deg[c]+1) for arbitrary
// neighbors c, so global dedupe must complete before any aggregate starts.
// ---------------------------------------------------------------------------
__global__ __launch_bounds__(256)
void compact_kernel(int* __restrict__ rowlist, unsigned int* __restrict__ deg) {
    __shared__ int buf[4][64];
    int w    = threadIdx.x >> 6;
    int lane = threadIdx.x & 63;
    int i    = blockIdx.x * 4 + w;
    int n = (int)deg[i];
    if (n > 64) n = 64;
    int t = -1;
    if (lane < n) t = rowlist[(size_t)i * CAP + lane];
    buf[w][lane] = t;
    __syncthreads();
    bool keep = false;
    if (lane < n) {
        keep = true;
        for (int j = 0; j < lane; ++j) {
            if (buf[w][j] == t) { keep = false; break; }
        }
    }
    unsigned long long m = __ballot(keep);
    int pos = __popcll(m & ((1ull << lane) - 1ull));
    if (keep && pos != lane) rowlist[(size_t)i * CAP + pos] = t;  // reads all done (own reg)
    if (lane == 0) deg[i] = (unsigned int)__popcll(m);
}

// ---------------------------------------------------------------------------
// Kernel 3 (FUSED aggregate + GEMM): each block owns 16 output rows.
// Phase A: stage neighbor lists + dj = rsqrt(deg+1) in LDS; one 32-lane team
//   per row gathers x via float4, computes y[i] = di*(di*x[i] + sum_j dj*x[j])
//   and stores split-bf16 Y tile in LDS.
//   Self-edge j==i appears in list with dj==di plus identity term -> A~[i][i]=2. OK.
// Phase B: 8 waves; wave w computes out[16 x 32] cols w*32.. via split-bf16
//   MFMA (Yh*Wh + Yh*Wl + Yl*Wh; Yl*Wl ~1e-5 rel, dropped).
// ---------------------------------------------------------------------------
__global__ __launch_bounds__(512)
void fused_agg_gemm(const int* __restrict__ rowlist,
                    const unsigned int* __restrict__ deg,
                    const float* __restrict__ x,
                    const unsigned short* __restrict__ Wh,
                    const unsigned short* __restrict__ Wl,
                    float* __restrict__ out) {
    __shared__ int            nrow[RPB];
    __shared__ float          sdi[RPB];
    __shared__ int            cols[RPB][CAP];
    __shared__ float          djs[RPB][CAP];
    __shared__ unsigned short Yh[RPB][YLD];
    __shared__ unsigned short Yl[RPB][YLD];

    int tid = threadIdx.x;
    int m0  = blockIdx.x * RPB;

    if (tid < RPB) {
        unsigned int dg = deg[m0 + tid];   // distinct count (post-compact)
        int n = (int)dg; if (n > CAP) n = CAP;
        nrow[tid] = n;
        sdi[tid]  = rsqrtf((float)dg + 1.0f);
    }
    __syncthreads();

    // stage neighbor ids + dj factors (scattered deg loads, ~272 per block)
    for (int e = tid; e < RPB * CAP; e += 512) {
        int r = e / CAP, k = e - r * CAP;
        if (k < nrow[r]) {
            int c = rowlist[(size_t)(m0 + r) * CAP + k];
            cols[r][k] = c;
            djs[r][k]  = rsqrtf((float)deg[c] + 1.0f);
        }
    }
    __syncthreads();

    // ---- Phase A: gather + normalize, one 32-lane team per row ----
    {
        int team = tid >> 5;       // row within tile (0..15)
        int l4   = tid & 31;       // float4 slot (32*4 = 128 dims)
        const float4* x4 = (const float4*)x;
        int   n    = nrow[team];
        float di   = sdi[team];
        float4 self = x4[(size_t)(m0 + team) * 32 + l4];
        float ax = 0.f, ay = 0.f, az = 0.f, aw = 0.f;
        int k = 0;
        for (; k + 2 <= n; k += 2) {           // unroll-by-2 for memory ILP
            float  d0 = djs[team][k];
            float  d1 = djs[team][k + 1];
            float4 v0 = x4[(size_t)cols[team][k]     * 32 + l4];
            float4 v1 = x4[(size_t)cols[team][k + 1] * 32 + l4];
            ax += d0 * v0.x + d1 * v1.x;
            ay += d0 * v0.y + d1 * v1.y;
            az += d0 * v0.z + d1 * v1.z;
            aw += d0 * v0.w + d1 * v1.w;
        }
        if (k < n) {
            float  d0 = djs[team][k];
            float4 v0 = x4[(size_t)cols[team][k] * 32 + l4];
            ax += d0 * v0.x; ay += d0 * v0.y; az += d0 * v0.z; aw += d0 * v0.w;
        }
        float vx = di * (di * self.x + ax);
        float vy = di * (di * self.y + ay);
        float vz = di * (di * self.z + az);
        float vw = di * (di * self.w + aw);
        ushort4 h, l;
        h.x = f2bf(vx); l.x = f2bf(vx - bf2f(h.x));
        h.y = f2bf(vy); l.y = f2bf(vy - bf2f(h.y));
        h.z = f2bf(vz); l.z = f2bf(vz - bf2f(h.z));
        h.w = f2bf(vw); l.w = f2bf(vw - bf2f(h.w));
        *(ushort4*)&Yh[team][l4 * 4] = h;
        *(ushort4*)&Yl[team][l4 * 4] = l;
    }
    __syncthreads();

    // ---- Phase B: 16x256 = Y[16][128] @ W[256][128]^T, split-bf16 MFMA ----
    // Frag layout (16x16x32_bf16): A[m=lane&15][k=quad*8+j]; C/D col=lane&15,
    // row=quad*4+reg (same conventions as the previously-verified gemm_kernel).
    {
        int wave = tid >> 6;      // 0..7, owns cols wave*32 .. wave*32+31
        int lane = tid & 63;
        int quad = lane >> 4;
        int l16  = lane & 15;

        f32x4 acc[2] = {{0,0,0,0},{0,0,0,0}};
#pragma unroll
        for (int ks = 0; ks < 4; ++ks) {
            bf16x8 ah = *(const bf16x8*)&Yh[l16][ks * 32 + quad * 8];
            bf16x8 al = *(const bf16x8*)&Yl[l16][ks * 32 + quad * 8];
#pragma unroll
            for (int ct = 0; ct < 2; ++ct) {
                int hcol = wave * 32 + ct * 16 + l16;
                bf16x8 bh = *(const bf16x8*)(Wh + (size_t)hcol * NODE_DIM + ks * 32 + quad * 8);
                bf16x8 bl = *(const bf16x8*)(Wl + (size_t)hcol * NODE_DIM + ks * 32 + quad * 8);
                acc[ct] = __builtin_amdgcn_mfma_f32_16x16x32_bf16(ah, bh, acc[ct], 0, 0, 0);
                acc[ct] = __builtin_amdgcn_mfma_f32_16x16x32_bf16(ah, bl, acc[ct], 0, 0, 0);
                acc[ct] = __builtin_amdgcn_mfma_f32_16x16x32_bf16(al, bh, acc[ct], 0, 0, 0);
            }
        }
#pragma unroll
        for (int ct = 0; ct < 2; ++ct) {
#pragma unroll
            for (int r = 0; r < 4; ++r) {
                out[(size_t)(m0 + quad * 4 + r) * HIDDEN_DIM + wave * 32 + ct * 16 + l16] = acc[ct][r];
            }
        }
    }
}

extern "C" void kernel_launch(void* const* d_in, const int* in_sizes, int n_in,
                              void* d_out, int out_size, void* d_ws, size_t ws_size,
                              hipStream_t stream) {
    const float* x = (const float*)d_in[0];
    const int*   e = (const int*)d_in[1];   // edge_index delivered as int32 [2, E]
    const float* W = (const float*)d_in[2];
    float*       out = (float*)d_out;
    int E = in_sizes[1] / 2;

    // ws layout: deg 32KB | rowlist 3MB | wh 64KB | wl 64KB   (no 8MB bitmask)
    unsigned int*   deg     = (unsigned int*)d_ws;
    int*            rowlist = (int*)(deg + N_NODES);
    unsigned short* wh      = (unsigned short*)(rowlist + (size_t)N_NODES * CAP);
    unsigned short* wl      = wh + (size_t)HIDDEN_DIM * NODE_DIM;

    // zero deg only (32 KB); rowlist needs no clear (guarded by deg counts)
    hipMemsetAsync(d_ws, 0, (size_t)N_NODES * sizeof(unsigned int), stream);

    int nEdgeBlocks = (E + 255) / 256;
    int nWBlocks    = (HIDDEN_DIM * NODE_DIM / 4 + 255) / 256;   // 32
    append_kernel<<<nEdgeBlocks + nWBlocks, 256, 0, stream>>>(e, deg, rowlist,
                                                              W, wh, wl, E, nEdgeBlocks);
    compact_kernel<<<N_NODES / 4, 256, 0, stream>>>(rowlist, deg);
    fused_agg_gemm<<<N_NODES / RPB, 512, 0, stream>>>(rowlist, deg, x, wh, wl, out);
}